// Round 1
// baseline (713.043 us; speedup 1.0000x reference)
//
#include <hip/hip_runtime.h>

// RelationMemory fused fp32 implementation (Round 1: correctness-first baseline).
// Structure:
//   k_embed    : se = s@W_es^T+b, te = t@W_et^T+b                      [128,128]
//   k_proj_mem : proj = memory_s@W_tsq^T+b_tsq  -> d_out memory region (scratch!)
//   k_proj4    : m_t_v, m_t_q, m_t_s_v, m_t_s_q_pos                    [128,128] each
//   k_ht       : h_t[i,j] = l2norm(W_ht@(W_mt@relu(mtv[j]-mtq[i])+b)+b) -> ws
//   k_neg      : fused pos+neg: per (i,j) 17 rows:
//                  rel = relu(msv[j] - src)   (src = mspq[i] or proj[idx])
//                  r = W_mts@rel+b ; u = W_hts@r+b ; score = h_t . u/||u||
//                  out[i*B+j][row] = exp((score-1)/T)
//   k_memcopy  : memory_s -> d_out memory region (overwrites proj scratch)
//   k_memupd   : scatter momentum rows (numpy last-wins for duplicate y)

#define BB   128
#define DDS  1024
#define DD   128
#define KK   16
#define NMEM 100000

static constexpr float INV_T = 1.0f / 0.07f;

// ws layout (float offsets)
#define WS_SE    0
#define WS_TE    16384
#define WS_MTV   32768
#define WS_MTQ   49152
#define WS_MSV   65536
#define WS_MSPQ  81920
#define WS_HT    98304          // 16384*128 floats
#define OUT_MEM  278528         // 16384*17; memory_new region offset in d_out

// ---------------------------------------------------------------- k_embed
__global__ __launch_bounds__(128) void k_embed(
    const float* __restrict__ s, const float* __restrict__ t,
    const float* __restrict__ W_es, const float* __restrict__ b_es,
    const float* __restrict__ W_et, const float* __restrict__ b_et,
    float* __restrict__ ws)
{
    __shared__ float xs[1024];
    int bid = blockIdx.x;
    int which = bid >> 7;          // 0: se, 1: te
    int r = bid & 127;
    const float* x    = which ? (t + (long)r * DDS) : (s + (long)r * DDS);
    const float* W    = which ? W_et : W_es;
    const float* bias = which ? b_et : b_es;
    float* outp = ws + (which ? WS_TE : WS_SE) + r * DD;

    int tid = threadIdx.x;
    for (int i = tid; i < 1024; i += 128) xs[i] = x[i];
    __syncthreads();

    float acc = bias[tid];
    const float* Wr = W + (long)tid * 1024;
    #pragma unroll 8
    for (int k = 0; k < 1024; k += 4) {
        float4 xv = *(const float4*)&xs[k];
        float4 wv = *(const float4*)&Wr[k];
        acc = fmaf(xv.x, wv.x, fmaf(xv.y, wv.y, fmaf(xv.z, wv.z, fmaf(xv.w, wv.w, acc))));
    }
    outp[tid] = acc;
}

// ---------------------------------------------------------------- k_proj4
__global__ __launch_bounds__(128) void k_proj4(
    const float* __restrict__ W_tv,  const float* __restrict__ b_tv,
    const float* __restrict__ W_tq,  const float* __restrict__ b_tq,
    const float* __restrict__ W_tsv, const float* __restrict__ b_tsv,
    const float* __restrict__ W_tsq, const float* __restrict__ b_tsq,
    float* __restrict__ ws)
{
    int bid = blockIdx.x;
    int which = bid >> 7;          // 0..3
    int r = bid & 127;
    const float *W, *bias, *in;
    float* outp;
    switch (which) {
        case 0:  W = W_tv;  bias = b_tv;  in = ws + WS_TE; outp = ws + WS_MTV;  break;
        case 1:  W = W_tq;  bias = b_tq;  in = ws + WS_TE; outp = ws + WS_MTQ;  break;
        case 2:  W = W_tsv; bias = b_tsv; in = ws + WS_TE; outp = ws + WS_MSV;  break;
        default: W = W_tsq; bias = b_tsq; in = ws + WS_SE; outp = ws + WS_MSPQ; break;
    }
    int d = threadIdx.x;
    const float* xr = in + r * DD;
    const float* Wr = W + d * DD;
    float acc = bias[d];
    #pragma unroll
    for (int k = 0; k < DD; k += 4) {
        float4 xv = *(const float4*)&xr[k];
        float4 wv = *(const float4*)&Wr[k];
        acc = fmaf(xv.x, wv.x, fmaf(xv.y, wv.y, fmaf(xv.z, wv.z, fmaf(xv.w, wv.w, acc))));
    }
    outp[r * DD + d] = acc;
}

// ---------------------------------------------------------------- k_proj_mem
// proj[n] = memory_s[n] @ W_tsq^T + b_tsq, n in [0, NMEM). 256 thr, 64 rows/blk.
__global__ __launch_bounds__(256) void k_proj_mem(
    const float* __restrict__ mem, const float* __restrict__ W,
    const float* __restrict__ bias, float* __restrict__ proj)
{
    __shared__ float Wt[16384];    // Wt[k*128+d] = W[d*128+k]
    int tid = threadIdx.x;
    for (int i = tid; i < 16384; i += 256) {
        int kk2 = i >> 7, dd2 = i & 127;
        Wt[i] = W[dd2 * 128 + kk2];
    }
    __syncthreads();

    int lane = tid & 63, w = tid >> 6;
    float b0 = bias[lane], b1 = bias[lane + 64];
    int row0 = blockIdx.x * 64 + w * 16;

    for (int g = 0; g < 4; ++g) {
        int n0 = row0 + g * 4;
        float a0[4], a1[4];
        #pragma unroll
        for (int r = 0; r < 4; ++r) { a0[r] = b0; a1[r] = b1; }
        const float* m[4];
        #pragma unroll
        for (int r = 0; r < 4; ++r) {
            int n = n0 + r; if (n > NMEM - 1) n = NMEM - 1;
            m[r] = mem + (long)n * 128;
        }
        #pragma unroll 2
        for (int k = 0; k < 128; k += 4) {
            float w00 = Wt[(k+0)*128 + lane],      w01 = Wt[(k+1)*128 + lane];
            float w02 = Wt[(k+2)*128 + lane],      w03 = Wt[(k+3)*128 + lane];
            float w10 = Wt[(k+0)*128 + 64 + lane], w11 = Wt[(k+1)*128 + 64 + lane];
            float w12 = Wt[(k+2)*128 + 64 + lane], w13 = Wt[(k+3)*128 + 64 + lane];
            float4 xv[4];
            #pragma unroll
            for (int r = 0; r < 4; ++r) xv[r] = *(const float4*)&m[r][k];
            #pragma unroll
            for (int r = 0; r < 4; ++r) {
                a0[r] = fmaf(xv[r].x, w00, fmaf(xv[r].y, w01, fmaf(xv[r].z, w02, fmaf(xv[r].w, w03, a0[r]))));
                a1[r] = fmaf(xv[r].x, w10, fmaf(xv[r].y, w11, fmaf(xv[r].z, w12, fmaf(xv[r].w, w13, a1[r]))));
            }
        }
        #pragma unroll
        for (int r = 0; r < 4; ++r) {
            int n = n0 + r;
            if (n < NMEM) {
                proj[(long)n * 128 + lane]      = a0[r];
                proj[(long)n * 128 + 64 + lane] = a1[r];
            }
        }
    }
}

// ------------------------------------------------- shared matvec helper
// o[d] = bias[d] + sum_k buf[r][k] * W[d][k], Wt in LDS k-major (conflict-free)
template <int G>
__device__ inline void matvec_lds(const float* __restrict__ Wt, const float* __restrict__ buf,
                                  float bias0, float bias1,
                                  float (&o0)[G], float (&o1)[G], int lane)
{
    #pragma unroll
    for (int r = 0; r < G; ++r) { o0[r] = bias0; o1[r] = bias1; }
    #pragma unroll 2
    for (int k = 0; k < 128; k += 4) {
        float w00 = Wt[(k+0)*128 + lane],      w01 = Wt[(k+1)*128 + lane];
        float w02 = Wt[(k+2)*128 + lane],      w03 = Wt[(k+3)*128 + lane];
        float w10 = Wt[(k+0)*128 + 64 + lane], w11 = Wt[(k+1)*128 + 64 + lane];
        float w12 = Wt[(k+2)*128 + 64 + lane], w13 = Wt[(k+3)*128 + 64 + lane];
        #pragma unroll
        for (int r = 0; r < G; ++r) {
            float4 x = *(const float4*)&buf[r * 128 + k];
            o0[r] = fmaf(x.x, w00, fmaf(x.y, w01, fmaf(x.z, w02, fmaf(x.w, w03, o0[r]))));
            o1[r] = fmaf(x.x, w10, fmaf(x.y, w11, fmaf(x.z, w12, fmaf(x.w, w13, o1[r]))));
        }
    }
}

// ---------------------------------------------------------------- k_ht
// h_t[p] for p = i*128+j. 512 thr, 64 pairs/block, 8 per wave in 2 passes of 4.
__global__ __launch_bounds__(512, 2) void k_ht(
    const float* __restrict__ W_mt, const float* __restrict__ b_mt,
    const float* __restrict__ W_ht, const float* __restrict__ b_ht,
    float* __restrict__ ws)
{
    __shared__ float Wt1[16384], Wt2[16384];
    __shared__ float buf[8][4 * 128];
    int tid = threadIdx.x;
    for (int i = tid; i < 16384; i += 512) {
        int kk2 = i >> 7, dd2 = i & 127;
        Wt1[i] = W_mt[dd2 * 128 + kk2];
        Wt2[i] = W_ht[dd2 * 128 + kk2];
    }
    __syncthreads();

    int lane = tid & 63, w = tid >> 6;
    const float* mtv = ws + WS_MTV;
    const float* mtq = ws + WS_MTQ;
    float* ht = ws + WS_HT;
    float bm0 = b_mt[lane], bm1 = b_mt[64 + lane];
    float bh0 = b_ht[lane], bh1 = b_ht[64 + lane];
    float* mybuf = &buf[w][0];
    int pbase = blockIdx.x * 64 + w * 8;

    for (int pass = 0; pass < 2; ++pass) {
        int p0 = pbase + pass * 4;
        #pragma unroll
        for (int r = 0; r < 4; ++r) {
            int p = p0 + r; int i = p >> 7, j = p & 127;
            mybuf[r*128 + lane]      = fmaxf(mtv[j*128 + lane]      - mtq[i*128 + lane],      0.f);
            mybuf[r*128 + 64 + lane] = fmaxf(mtv[j*128 + 64 + lane] - mtq[i*128 + 64 + lane], 0.f);
        }
        float r0[4], r1[4];
        matvec_lds<4>(Wt1, mybuf, bm0, bm1, r0, r1, lane);
        #pragma unroll
        for (int r = 0; r < 4; ++r) { mybuf[r*128 + lane] = r0[r]; mybuf[r*128 + 64 + lane] = r1[r]; }
        float u0[4], u1[4];
        matvec_lds<4>(Wt2, mybuf, bh0, bh1, u0, u1, lane);
        #pragma unroll
        for (int r = 0; r < 4; ++r) {
            float uu = u0[r]*u0[r] + u1[r]*u1[r];
            #pragma unroll
            for (int mq = 32; mq; mq >>= 1) uu += __shfl_xor(uu, mq);
            float rn = rsqrtf(uu);
            int p = p0 + r;
            ht[(long)p*128 + lane]      = u0[r] * rn;
            ht[(long)p*128 + 64 + lane] = u1[r] * rn;
        }
    }
}

// ---------------------------------------------------------------- k_neg (fused pos+neg)
template <int G>
__device__ inline void neg_pass(int base, int i, const int* __restrict__ ip,
                                const float* __restrict__ mspq, const float* __restrict__ proj,
                                float v0, float v1, float h0, float h1,
                                const float* __restrict__ Wt1, const float* __restrict__ Wt2,
                                float bm0, float bm1, float bh0, float bh1,
                                float* __restrict__ mybuf, int lane, float* __restrict__ outp)
{
    #pragma unroll
    for (int r = 0; r < G; ++r) {
        int gr = base + r;
        const float* src;
        if (gr == 0) src = mspq + (long)i * 128;
        else         src = proj + (long)ip[gr - 1] * 128;
        float s0 = src[lane], s1 = src[64 + lane];
        mybuf[r*128 + lane]      = fmaxf(v0 - s0, 0.f);
        mybuf[r*128 + 64 + lane] = fmaxf(v1 - s1, 0.f);
    }
    float r0[G], r1[G];
    matvec_lds<G>(Wt1, mybuf, bm0, bm1, r0, r1, lane);
    #pragma unroll
    for (int r = 0; r < G; ++r) { mybuf[r*128 + lane] = r0[r]; mybuf[r*128 + 64 + lane] = r1[r]; }
    float u0[G], u1[G];
    matvec_lds<G>(Wt2, mybuf, bh0, bh1, u0, u1, lane);
    #pragma unroll
    for (int r = 0; r < G; ++r) {
        float hu = h0*u0[r] + h1*u1[r];
        float uu = u0[r]*u0[r] + u1[r]*u1[r];
        #pragma unroll
        for (int mq = 32; mq; mq >>= 1) {
            hu += __shfl_xor(hu, mq);
            uu += __shfl_xor(uu, mq);
        }
        if (lane == 0) {
            float sc = hu * rsqrtf(uu);
            outp[base + r] = __expf((sc - 1.0f) * INV_T);
        }
    }
}

__global__ __launch_bounds__(512, 2) void k_neg(
    const float* __restrict__ ws, const int* __restrict__ idx,
    const float* __restrict__ W_mts, const float* __restrict__ b_mts,
    const float* __restrict__ W_hts, const float* __restrict__ b_hts,
    const float* __restrict__ proj, float* __restrict__ out)
{
    __shared__ float Wt1[16384], Wt2[16384];
    __shared__ float buf[8][6 * 128];
    int tid = threadIdx.x;
    for (int i = tid; i < 16384; i += 512) {
        int kk2 = i >> 7, dd2 = i & 127;
        Wt1[i] = W_mts[dd2 * 128 + kk2];
        Wt2[i] = W_hts[dd2 * 128 + kk2];
    }
    __syncthreads();

    int lane = tid & 63, w = tid >> 6;
    const float* msv  = ws + WS_MSV;
    const float* mspq = ws + WS_MSPQ;
    const float* ht   = ws + WS_HT;
    float bm0 = b_mts[lane], bm1 = b_mts[64 + lane];
    float bh0 = b_hts[lane], bh1 = b_hts[64 + lane];
    float* mybuf = &buf[w][0];

    for (int q = 0; q < 4; ++q) {
        int p = blockIdx.x * 32 + w * 4 + q;    // pair id: i*128+j
        int i = p >> 7, j = p & 127;
        float h0 = ht[(long)p*128 + lane], h1 = ht[(long)p*128 + 64 + lane];
        float v0 = msv[j*128 + lane],      v1 = msv[j*128 + 64 + lane];
        const int* ip = idx + (long)p * 17;
        float* outp = out + (long)p * 17;
        neg_pass<6>(0,  i, ip, mspq, proj, v0, v1, h0, h1, Wt1, Wt2, bm0, bm1, bh0, bh1, mybuf, lane, outp);
        neg_pass<6>(6,  i, ip, mspq, proj, v0, v1, h0, h1, Wt1, Wt2, bm0, bm1, bh0, bh1, mybuf, lane, outp);
        neg_pass<5>(12, i, ip, mspq, proj, v0, v1, h0, h1, Wt1, Wt2, bm0, bm1, bh0, bh1, mybuf, lane, outp);
    }
}

// ---------------------------------------------------------------- memory update
__global__ __launch_bounds__(256) void k_memcopy(const float* __restrict__ mem, float* __restrict__ dst)
{
    long i = (long)blockIdx.x * blockDim.x + threadIdx.x;
    long n4 = (long)NMEM * 128 / 4;
    long stride = (long)gridDim.x * blockDim.x;
    for (; i < n4; i += stride)
        ((float4*)dst)[i] = ((const float4*)mem)[i];
}

__global__ __launch_bounds__(128) void k_memupd(
    const float* __restrict__ mem, const float* __restrict__ se,
    const int* __restrict__ y, float* __restrict__ dst)
{
    int b = blockIdx.x;
    int d = threadIdx.x;
    int yb = y[b];
    // numpy-style last-write-wins on duplicate indices
    for (int b2 = b + 1; b2 < BB; ++b2)
        if (y[b2] == yb) return;

    float ab = 0.5f * mem[(long)yb * 128 + d] + 0.5f * se[b * 128 + d];
    float ss = ab * ab;
    #pragma unroll
    for (int mq = 32; mq; mq >>= 1) ss += __shfl_xor(ss, mq);
    __shared__ float partial[2];
    if ((d & 63) == 0) partial[d >> 6] = ss;
    __syncthreads();
    float tot = partial[0] + partial[1];
    dst[(long)yb * 128 + d] = ab * rsqrtf(tot);
}

// ---------------------------------------------------------------- launch
extern "C" void kernel_launch(void* const* d_in, const int* in_sizes, int n_in,
                              void* d_out, int out_size, void* d_ws, size_t ws_size,
                              hipStream_t stream)
{
    const float* s     = (const float*)d_in[0];
    const float* t     = (const float*)d_in[1];
    const int*   y     = (const int*)  d_in[2];
    const int*   idx   = (const int*)  d_in[3];
    const float* mem   = (const float*)d_in[4];
    const float* W_es  = (const float*)d_in[5];  const float* b_es  = (const float*)d_in[6];
    const float* W_et  = (const float*)d_in[7];  const float* b_et  = (const float*)d_in[8];
    const float* W_tv  = (const float*)d_in[9];  const float* b_tv  = (const float*)d_in[10];
    const float* W_tq  = (const float*)d_in[11]; const float* b_tq  = (const float*)d_in[12];
    const float* W_tsv = (const float*)d_in[13]; const float* b_tsv = (const float*)d_in[14];
    const float* W_tsq = (const float*)d_in[15]; const float* b_tsq = (const float*)d_in[16];
    const float* W_mt  = (const float*)d_in[17]; const float* b_mt  = (const float*)d_in[18];
    const float* W_mts = (const float*)d_in[19]; const float* b_mts = (const float*)d_in[20];
    const float* W_ht  = (const float*)d_in[21]; const float* b_ht  = (const float*)d_in[22];
    const float* W_hts = (const float*)d_in[23]; const float* b_hts = (const float*)d_in[24];

    float* out  = (float*)d_out;
    float* ws   = (float*)d_ws;
    float* proj = out + OUT_MEM;   // scratch in d_out's memory_new region; overwritten later

    k_embed   <<<256, 128, 0, stream>>>(s, t, W_es, b_es, W_et, b_et, ws);
    k_proj_mem<<<1563, 256, 0, stream>>>(mem, W_tsq, b_tsq, proj);
    k_proj4   <<<512, 128, 0, stream>>>(W_tv, b_tv, W_tq, b_tq, W_tsv, b_tsv, W_tsq, b_tsq, ws);
    k_ht      <<<256, 512, 0, stream>>>(W_mt, b_mt, W_ht, b_ht, ws);
    k_neg     <<<512, 512, 0, stream>>>(ws, idx, W_mts, b_mts, W_hts, b_hts, proj, out);
    k_memcopy <<<2048, 256, 0, stream>>>(mem, out + OUT_MEM);
    k_memupd  <<<128, 128, 0, stream>>>(mem, ws + WS_SE, y, out + OUT_MEM);
}

// Round 2
// 172.995 us; speedup vs baseline: 4.1218x; 4.1218x over previous
//
#include <hip/hip_runtime.h>

// RelationMemory — Round 2: algebraic weight composition + split-bf16 MFMA.
//
// Key algebra: linear(linear(x, Wm, bm), Wh, bh) == linear(x, Wh@Wm, Wh@bm+bh)
// (no nonlinearity between) -> ONE 128x128 matvec per row instead of two.
//
// MFMA: v_mfma_f32_16x16x32_bf16, fp32 emulated as bf16 hi/lo split with
// 3 products (ah*bh + ah*bl + al*bh), rel err ~2^-17 (fp32-class).
// Fragment layouts (AMD matrix-core doc + learn_hip m89-verified C/D):
//   A: lane l holds row (l&15),        k = (l>>4)*8 + e   (8 bf16 = short8)
//   B: lane l holds col (l&15),        k = (l>>4)*8 + e
//   D: lane l reg r -> row (l>>4)*4+r, col (l&15)         (f32x4)
// Weights are pre-composed + pre-split + stored in B-fragment order so LDS
// reads are linear ds_read_b128 (byte addr = frag*1024 + lane*16, conflict-free).

#define BB   128
#define DD   128
#define KK   16
#define NMEM 100000

static constexpr float INV_T = 1.0f / 0.07f;

// ws layout (float offsets)
#define WS_SE    0
#define WS_TE    16384
#define WS_MTV   32768
#define WS_MTQ   49152
#define WS_MSV   65536
#define WS_MSPQ  81920
#define WS_HT    98304            // 16384*128 floats -> ends 2195456
#define FR_TS_HI 2195456          // each frag array: 16384 shorts = 8192 floats
#define FR_TS_LO 2203648
#define FR_T_HI  2211840
#define FR_T_LO  2220032
#define FR_Q_HI  2228224
#define FR_Q_LO  2236416
#define BC_TS    2244608          // 128 floats
#define BC_T     2244736
#define OUT_MEM  278528           // memory_new offset in d_out

typedef __attribute__((ext_vector_type(8))) short short8v;
typedef __attribute__((ext_vector_type(4))) float f32x4;

__device__ inline unsigned short f2bf(float x) {
    unsigned u = __float_as_uint(x);
    unsigned r = u + 0x7fffu + ((u >> 16) & 1u);
    return (unsigned short)(r >> 16);
}
__device__ inline float bf2f(unsigned short h) {
    return __uint_as_float(((unsigned)h) << 16);
}

// write one weight element into B-fragment order (hi/lo split)
__device__ inline void frag_write(int d, int k, float x, short* FH, short* FL) {
    int t = d >> 4, col = d & 15, c = k >> 5, kg = (k >> 3) & 3, e = k & 7;
    int a2 = (((t * 4 + c) * 4 + kg) * 16 + col) * 8 + e;
    unsigned short h = f2bf(x);
    FH[a2] = (short)h;
    FL[a2] = (short)f2bf(x - bf2f(h));
}

// ---------------------------------------------------------------- k_compose
// block 0: Wc_ts = W_hts@W_mts, bc_ts = W_hts@b_mts + b_hts  -> FR_TS, BC_TS
// block 1: Wc_t  = W_ht @W_mt,  bc_t  = W_ht @b_mt  + b_ht   -> FR_T,  BC_T
// block 2: reorder/split W_tsq                               -> FR_Q
__global__ __launch_bounds__(256) void k_compose(
    const float* __restrict__ W_mts, const float* __restrict__ b_mts,
    const float* __restrict__ W_hts, const float* __restrict__ b_hts,
    const float* __restrict__ W_mt,  const float* __restrict__ b_mt,
    const float* __restrict__ W_ht,  const float* __restrict__ b_ht,
    const float* __restrict__ W_tsq, float* __restrict__ ws)
{
    int which = blockIdx.x;
    int tid = threadIdx.x;
    if (which == 2) {
        short* FH = (short*)(ws + FR_Q_HI);
        short* FL = (short*)(ws + FR_Q_LO);
        for (int q = 0; q < 64; ++q) {
            int el = tid * 64 + q;
            frag_write(el >> 7, el & 127, W_tsq[el], FH, FL);
        }
        return;
    }
    const float* A    = which ? W_ht : W_hts;
    const float* Bm   = which ? W_mt : W_mts;
    const float* bin  = which ? b_mt : b_mts;
    const float* bout = which ? b_ht : b_hts;
    short* FH = (short*)(ws + (which ? FR_T_HI : FR_TS_HI));
    short* FL = (short*)(ws + (which ? FR_T_LO : FR_TS_LO));
    float* BC = ws + (which ? BC_T : BC_TS);

    __shared__ float Bs[16384];
    for (int i2 = tid; i2 < 16384; i2 += 256) Bs[i2] = Bm[i2];
    __syncthreads();

    int d = tid >> 1;
    int k0 = (tid & 1) * 64;
    float acc2[64];
    #pragma unroll
    for (int q = 0; q < 64; ++q) acc2[q] = 0.f;
    for (int m = 0; m < 128; ++m) {
        float a = A[d * 128 + m];
        const float* brow = &Bs[m * 128 + k0];
        #pragma unroll
        for (int q = 0; q < 64; ++q) acc2[q] = fmaf(a, brow[q], acc2[q]);
    }
    #pragma unroll
    for (int q = 0; q < 64; ++q) frag_write(d, k0 + q, acc2[q], FH, FL);

    if (tid < 128) {
        float a = bout[tid];
        for (int m = 0; m < 128; ++m) a = fmaf(A[tid * 128 + m], bin[m], a);
        BC[tid] = a;
    }
}

// ---------------------------------------------------------------- k_embed
__global__ __launch_bounds__(128) void k_embed(
    const float* __restrict__ s, const float* __restrict__ t,
    const float* __restrict__ W_es, const float* __restrict__ b_es,
    const float* __restrict__ W_et, const float* __restrict__ b_et,
    float* __restrict__ ws)
{
    __shared__ float xs[1024];
    int bid = blockIdx.x;
    int which = bid >> 7;
    int r = bid & 127;
    const float* x    = which ? (t + (long)r * 1024) : (s + (long)r * 1024);
    const float* W    = which ? W_et : W_es;
    const float* bias = which ? b_et : b_es;
    float* outp = ws + (which ? WS_TE : WS_SE) + r * DD;

    int tid = threadIdx.x;
    for (int i = tid; i < 1024; i += 128) xs[i] = x[i];
    __syncthreads();

    float acc = bias[tid];
    const float* Wr = W + (long)tid * 1024;
    #pragma unroll 8
    for (int k = 0; k < 1024; k += 4) {
        float4 xv = *(const float4*)&xs[k];
        float4 wv = *(const float4*)&Wr[k];
        acc = fmaf(xv.x, wv.x, fmaf(xv.y, wv.y, fmaf(xv.z, wv.z, fmaf(xv.w, wv.w, acc))));
    }
    outp[tid] = acc;
}

// ---------------------------------------------------------------- k_proj4
__global__ __launch_bounds__(128) void k_proj4(
    const float* __restrict__ W_tv,  const float* __restrict__ b_tv,
    const float* __restrict__ W_tq,  const float* __restrict__ b_tq,
    const float* __restrict__ W_tsv, const float* __restrict__ b_tsv,
    const float* __restrict__ W_tsq, const float* __restrict__ b_tsq,
    float* __restrict__ ws)
{
    int bid = blockIdx.x;
    int which = bid >> 7;
    int r = bid & 127;
    const float *W, *bias, *in;
    float* outp;
    switch (which) {
        case 0:  W = W_tv;  bias = b_tv;  in = ws + WS_TE; outp = ws + WS_MTV;  break;
        case 1:  W = W_tq;  bias = b_tq;  in = ws + WS_TE; outp = ws + WS_MTQ;  break;
        case 2:  W = W_tsv; bias = b_tsv; in = ws + WS_TE; outp = ws + WS_MSV;  break;
        default: W = W_tsq; bias = b_tsq; in = ws + WS_SE; outp = ws + WS_MSPQ; break;
    }
    int d = threadIdx.x;
    const float* xr = in + r * DD;
    const float* Wr = W + d * DD;
    float acc = bias[d];
    #pragma unroll
    for (int k = 0; k < DD; k += 4) {
        float4 xv = *(const float4*)&xr[k];
        float4 wv = *(const float4*)&Wr[k];
        acc = fmaf(xv.x, wv.x, fmaf(xv.y, wv.y, fmaf(xv.z, wv.z, fmaf(xv.w, wv.w, acc))));
    }
    outp[r * DD + d] = acc;
}

// ------------------------------------------------- MFMA core: 16 rows x 128
// acc[t] (t = col-tile) = bc + sum_c split3( a[c] * B[t][c] )
__device__ inline void mfma_16rows(const short8v ah[4], const short8v al[4],
                                   const short* __restrict__ Bh, const short* __restrict__ Bl,
                                   const float* __restrict__ bc, int lane, f32x4 acc[8])
{
    #pragma unroll
    for (int t = 0; t < 8; ++t) {
        float b0 = bc[t * 16 + (lane & 15)];
        f32x4 a; a[0] = b0; a[1] = b0; a[2] = b0; a[3] = b0;
        #pragma unroll
        for (int c = 0; c < 4; ++c) {
            short8v bh = *(const short8v*)&Bh[((t * 4 + c) * 64 + lane) * 8];
            short8v bl = *(const short8v*)&Bl[((t * 4 + c) * 64 + lane) * 8];
            a = __builtin_amdgcn_mfma_f32_16x16x32_bf16(al[c], bh, a, 0, 0, 0);
            a = __builtin_amdgcn_mfma_f32_16x16x32_bf16(ah[c], bl, a, 0, 0, 0);
            a = __builtin_amdgcn_mfma_f32_16x16x32_bf16(ah[c], bh, a, 0, 0, 0);
        }
        acc[t] = a;
    }
}

// split fp32 x -> (hi, lo) bf16 and store into fragment slot e
__device__ inline void split_to(short8v& h8, short8v& l8, int e, float x) {
    unsigned short h = f2bf(x);
    h8[e] = (short)h;
    l8[e] = (short)f2bf(x - bf2f(h));
}

// ---------------------------------------------------------------- k_projmem_mfma
// proj[n] = mem[n] @ W_tsq^T + b_tsq  (100000 rows = 6250 groups)
__global__ __launch_bounds__(512, 2) void k_projmem_mfma(
    const float* __restrict__ mem, const float* __restrict__ b_tsq,
    const float* __restrict__ ws, float* __restrict__ proj)
{
    __shared__ short Bh[16384], Bl[16384];
    const short* frh = (const short*)(ws + FR_Q_HI);
    const short* frl = (const short*)(ws + FR_Q_LO);
    int tid = threadIdx.x;
    for (int i2 = tid; i2 < 2048; i2 += 512) {
        ((uint4*)Bh)[i2] = ((const uint4*)frh)[i2];
        ((uint4*)Bl)[i2] = ((const uint4*)frl)[i2];
    }
    __syncthreads();

    int lane = tid & 63, w = tid >> 6;
    int g = blockIdx.x * 8 + w;
    if (g >= 6250) return;

    int rowA = g * 16 + (lane & 15);
    int kg = (lane >> 4) * 8;
    const float* src = mem + (long)rowA * 128;
    short8v ah[4], al[4];
    #pragma unroll
    for (int c = 0; c < 4; ++c) {
        int ko = c * 32 + kg;
        float xv[8];
        *(float4*)&xv[0] = *(const float4*)&src[ko];
        *(float4*)&xv[4] = *(const float4*)&src[ko + 4];
        #pragma unroll
        for (int e = 0; e < 8; ++e) split_to(ah[c], al[c], e, xv[e]);
    }
    f32x4 acc[8];
    mfma_16rows(ah, al, Bh, Bl, b_tsq, lane, acc);

    int rq = lane >> 4;
    #pragma unroll
    for (int r = 0; r < 4; ++r) {
        long rho = g * 16 + rq * 4 + r;
        #pragma unroll
        for (int t = 0; t < 8; ++t)
            proj[rho * 128 + t * 16 + (lane & 15)] = acc[t][r];
    }
}

// ---------------------------------------------------------------- k_ht_mfma
// h_t[p] = l2norm(Wc_t @ relu(mtv[j]-mtq[i]) + bc_t), 16384 pairs = 1024 groups
__global__ __launch_bounds__(512, 2) void k_ht_mfma(float* __restrict__ ws)
{
    __shared__ short Bh[16384], Bl[16384];
    const short* frh = (const short*)(ws + FR_T_HI);
    const short* frl = (const short*)(ws + FR_T_LO);
    int tid = threadIdx.x;
    for (int i2 = tid; i2 < 2048; i2 += 512) {
        ((uint4*)Bh)[i2] = ((const uint4*)frh)[i2];
        ((uint4*)Bl)[i2] = ((const uint4*)frl)[i2];
    }
    __syncthreads();

    const float* mtv = ws + WS_MTV;
    const float* mtq = ws + WS_MTQ;
    const float* bc  = ws + BC_T;
    float* ht = ws + WS_HT;

    int lane = tid & 63, w = tid >> 6;
    int g = blockIdx.x * 8 + w;
    int p = g * 16 + (lane & 15);
    int i = p >> 7, j = p & 127;
    int kg = (lane >> 4) * 8;
    const float* vj = mtv + j * 128;
    const float* qi = mtq + i * 128;

    short8v ah[4], al[4];
    #pragma unroll
    for (int c = 0; c < 4; ++c) {
        int ko = c * 32 + kg;
        float vv[8], qq[8];
        *(float4*)&vv[0] = *(const float4*)&vj[ko];
        *(float4*)&vv[4] = *(const float4*)&vj[ko + 4];
        *(float4*)&qq[0] = *(const float4*)&qi[ko];
        *(float4*)&qq[4] = *(const float4*)&qi[ko + 4];
        #pragma unroll
        for (int e = 0; e < 8; ++e) split_to(ah[c], al[c], e, fmaxf(vv[e] - qq[e], 0.f));
    }
    f32x4 acc[8];
    mfma_16rows(ah, al, Bh, Bl, bc, lane, acc);

    int rq = lane >> 4;
    #pragma unroll
    for (int r = 0; r < 4; ++r) {
        long rho = g * 16 + rq * 4 + r;
        float s_uu = 0.f;
        #pragma unroll
        for (int t = 0; t < 8; ++t) { float u = acc[t][r]; s_uu = fmaf(u, u, s_uu); }
        #pragma unroll
        for (int m = 1; m < 16; m <<= 1) s_uu += __shfl_xor(s_uu, m);
        float rn = rsqrtf(s_uu);
        #pragma unroll
        for (int t = 0; t < 8; ++t)
            ht[rho * 128 + t * 16 + (lane & 15)] = acc[t][r] * rn;
    }
}

// ---------------------------------------------------------------- k_neg_mfma
// 278528 rows (= 16384 pairs x 17 slots) = 17408 groups of 16.
__global__ __launch_bounds__(512, 2) void k_neg_mfma(
    const float* __restrict__ ws, const int* __restrict__ idx,
    const float* __restrict__ proj, float* __restrict__ out)
{
    __shared__ short Bh[16384], Bl[16384];
    const short* frh = (const short*)(ws + FR_TS_HI);
    const short* frl = (const short*)(ws + FR_TS_LO);
    int tid = threadIdx.x;
    for (int i2 = tid; i2 < 2048; i2 += 512) {
        ((uint4*)Bh)[i2] = ((const uint4*)frh)[i2];
        ((uint4*)Bl)[i2] = ((const uint4*)frl)[i2];
    }
    __syncthreads();

    const float* msv  = ws + WS_MSV;
    const float* mspq = ws + WS_MSPQ;
    const float* ht   = ws + WS_HT;
    const float* bc   = ws + BC_TS;

    int lane = tid & 63, w = tid >> 6;
    int g = blockIdx.x * 8 + w;

    int rowA = g * 16 + (lane & 15);
    int p = rowA / 17;
    int slot = rowA - p * 17;
    int i = p >> 7, j = p & 127;
    const float* src = (slot == 0) ? (mspq + i * 128)
                                   : (proj + (long)idx[p * 17 + slot - 1] * 128);
    const float* vj = msv + j * 128;
    int kg = (lane >> 4) * 8;

    short8v ah[4], al[4];
    #pragma unroll
    for (int c = 0; c < 4; ++c) {
        int ko = c * 32 + kg;
        float vv[8], qq[8];
        *(float4*)&vv[0] = *(const float4*)&vj[ko];
        *(float4*)&vv[4] = *(const float4*)&vj[ko + 4];
        *(float4*)&qq[0] = *(const float4*)&src[ko];
        *(float4*)&qq[4] = *(const float4*)&src[ko + 4];
        #pragma unroll
        for (int e = 0; e < 8; ++e) split_to(ah[c], al[c], e, fmaxf(vv[e] - qq[e], 0.f));
    }
    f32x4 acc[8];
    mfma_16rows(ah, al, Bh, Bl, bc, lane, acc);

    int rq = lane >> 4;
    #pragma unroll
    for (int r = 0; r < 4; ++r) {
        int rho = g * 16 + rq * 4 + r;
        int pe = rho / 17;
        const float* hrow = ht + (long)pe * 128 + (lane & 15);
        float s_uu = 0.f, s_hu = 0.f;
        #pragma unroll
        for (int t = 0; t < 8; ++t) {
            float u = acc[t][r];
            s_uu = fmaf(u, u, s_uu);
            s_hu = fmaf(hrow[t * 16], u, s_hu);
        }
        #pragma unroll
        for (int m = 1; m < 16; m <<= 1) {
            s_uu += __shfl_xor(s_uu, m);
            s_hu += __shfl_xor(s_hu, m);
        }
        if ((lane & 15) == 0)
            out[rho] = __expf((s_hu * rsqrtf(s_uu) - 1.0f) * INV_T);
    }
}

// ---------------------------------------------------------------- memory update
__global__ __launch_bounds__(256) void k_memcopy(const float* __restrict__ mem, float* __restrict__ dst)
{
    long i = (long)blockIdx.x * blockDim.x + threadIdx.x;
    long n4 = (long)NMEM * 128 / 4;
    long stride = (long)gridDim.x * blockDim.x;
    for (; i < n4; i += stride)
        ((float4*)dst)[i] = ((const float4*)mem)[i];
}

__global__ __launch_bounds__(128) void k_memupd(
    const float* __restrict__ mem, const float* __restrict__ se,
    const int* __restrict__ y, float* __restrict__ dst)
{
    int b = blockIdx.x;
    int d = threadIdx.x;
    int yb = y[b];
    for (int b2 = b + 1; b2 < BB; ++b2)
        if (y[b2] == yb) return;

    float ab = 0.5f * mem[(long)yb * 128 + d] + 0.5f * se[b * 128 + d];
    float ss = ab * ab;
    #pragma unroll
    for (int mq = 32; mq; mq >>= 1) ss += __shfl_xor(ss, mq);
    __shared__ float partial[2];
    if ((d & 63) == 0) partial[d >> 6] = ss;
    __syncthreads();
    float tot = partial[0] + partial[1];
    dst[(long)yb * 128 + d] = ab * rsqrtf(tot);
}

// ---------------------------------------------------------------- launch
extern "C" void kernel_launch(void* const* d_in, const int* in_sizes, int n_in,
                              void* d_out, int out_size, void* d_ws, size_t ws_size,
                              hipStream_t stream)
{
    const float* s     = (const float*)d_in[0];
    const float* t     = (const float*)d_in[1];
    const int*   y     = (const int*)  d_in[2];
    const int*   idx   = (const int*)  d_in[3];
    const float* mem   = (const float*)d_in[4];
    const float* W_es  = (const float*)d_in[5];  const float* b_es  = (const float*)d_in[6];
    const float* W_et  = (const float*)d_in[7];  const float* b_et  = (const float*)d_in[8];
    const float* W_tv  = (const float*)d_in[9];  const float* b_tv  = (const float*)d_in[10];
    const float* W_tq  = (const float*)d_in[11]; const float* b_tq  = (const float*)d_in[12];
    const float* W_tsv = (const float*)d_in[13]; const float* b_tsv = (const float*)d_in[14];
    const float* W_tsq = (const float*)d_in[15]; const float* b_tsq = (const float*)d_in[16];
    const float* W_mt  = (const float*)d_in[17]; const float* b_mt  = (const float*)d_in[18];
    const float* W_mts = (const float*)d_in[19]; const float* b_mts = (const float*)d_in[20];
    const float* W_ht  = (const float*)d_in[21]; const float* b_ht  = (const float*)d_in[22];
    const float* W_hts = (const float*)d_in[23]; const float* b_hts = (const float*)d_in[24];

    float* out  = (float*)d_out;
    float* ws   = (float*)d_ws;
    float* proj = out + OUT_MEM;   // scratch in d_out's memory_new region

    k_compose     <<<3, 256, 0, stream>>>(W_mts, b_mts, W_hts, b_hts,
                                          W_mt, b_mt, W_ht, b_ht, W_tsq, ws);
    k_embed       <<<256, 128, 0, stream>>>(s, t, W_es, b_es, W_et, b_et, ws);
    k_projmem_mfma<<<782, 512, 0, stream>>>(mem, b_tsq, ws, proj);
    k_proj4       <<<512, 128, 0, stream>>>(W_tv, b_tv, W_tq, b_tq, W_tsv, b_tsv, W_tsq, b_tsq, ws);
    k_ht_mfma     <<<128, 512, 0, stream>>>(ws);
    k_neg_mfma    <<<2176, 512, 0, stream>>>(ws, idx, proj, out);
    k_memcopy     <<<2048, 256, 0, stream>>>(mem, out + OUT_MEM);
    k_memupd      <<<128, 128, 0, stream>>>(mem, ws + WS_SE, y, out + OUT_MEM);
}

// Round 3
// 160.630 us; speedup vs baseline: 4.4390x; 1.0770x over previous
//
#include <hip/hip_runtime.h>

// RelationMemory — Round 3: cheap Veltkamp split (v_perm pack), R=2 B-reuse in
// k_neg, projmem+memcopy fusion, parallelized compose, ILP fixes.
//
// Algebra: linear(linear(x,Wm,bm),Wh,bh) == linear(x, Wh@Wm, Wh@bm+bh).
// MFMA: v_mfma_f32_16x16x32_bf16, fp32 via bf16 hi/lo split, 3 products
// (ah*bh + ah*bl + al*bh); hi = half-up-round(x) (2 VALU), lo = x-hi exact,
// lo half-up-rounded; pairs packed with v_perm_b32. rel err ~2^-17.
// Fragment layouts (m89-verified): A row=lane&15,k=(lane>>4)*8+e;
// B col=lane&15; D row=(lane>>4)*4+r, col=lane&15.

#define BB   128
#define DD   128
#define KK   16
#define NMEM 100000

static constexpr float INV_T = 1.0f / 0.07f;

// ws layout (float offsets)
#define WS_SE    0
#define WS_TE    16384
#define WS_MTV   32768
#define WS_MTQ   49152
#define WS_MSV   65536
#define WS_MSPQ  81920
#define WS_HT    98304            // 16384*128 floats -> ends 2195456
#define FR_TS_HI 2195456          // each frag array: 16384 shorts = 8192 floats
#define FR_TS_LO 2203648
#define FR_T_HI  2211840
#define FR_T_LO  2220032
#define FR_Q_HI  2228224
#define FR_Q_LO  2236416
#define BC_TS    2244608          // 128 floats
#define BC_T     2244736
#define OUT_MEM  278528           // memory_new offset in d_out

typedef __attribute__((ext_vector_type(8))) short short8v;
typedef __attribute__((ext_vector_type(4))) float f32x4;

// ---- cheap split: hi = bf16 half-up(x), lo = bf16 half-up(x - hi) ----
__device__ inline void split2(float x0, float x1, unsigned& hi, unsigned& lo) {
    unsigned u0 = __float_as_uint(x0), u1 = __float_as_uint(x1);
    unsigned h0 = (u0 + 0x8000u) & 0xffff0000u;
    unsigned h1 = (u1 + 0x8000u) & 0xffff0000u;
    float l0 = x0 - __uint_as_float(h0);
    float l1 = x1 - __uint_as_float(h1);
    unsigned v0 = __float_as_uint(l0) + 0x8000u;
    unsigned v1 = __float_as_uint(l1) + 0x8000u;
    hi = __builtin_amdgcn_perm(h1, h0, 0x07060302u);   // (h1.top16<<16)|h0.top16
    lo = __builtin_amdgcn_perm(v1, v0, 0x07060302u);
}

// 8 floats (two float4) -> hi/lo bf16 fragments
__device__ inline void split8(const float4& x0, const float4& x1, short8v& h8, short8v& l8) {
    uint4 H, L;
    split2(x0.x, x0.y, H.x, L.x);
    split2(x0.z, x0.w, H.y, L.y);
    split2(x1.x, x1.y, H.z, L.z);
    split2(x1.z, x1.w, H.w, L.w);
    h8 = *(short8v*)&H;
    l8 = *(short8v*)&L;
}

// ---------------------------------------------------------------- k_compose
// blocks 0..7:  Wc_ts = W_hts@W_mts (+bias)  -> FR_TS, BC_TS
// blocks 8..15: Wc_t  = W_ht @W_mt  (+bias)  -> FR_T,  BC_T
// block 16:     reorder/split W_tsq          -> FR_Q
__global__ __launch_bounds__(256) void k_compose(
    const float* __restrict__ W_mts, const float* __restrict__ b_mts,
    const float* __restrict__ W_hts, const float* __restrict__ b_hts,
    const float* __restrict__ W_mt,  const float* __restrict__ b_mt,
    const float* __restrict__ W_ht,  const float* __restrict__ b_ht,
    const float* __restrict__ W_tsq, float* __restrict__ ws)
{
    int bid = blockIdx.x;
    int tid = threadIdx.x;
    if (bid == 16) {
        short* FH = (short*)(ws + FR_Q_HI);
        short* FL = (short*)(ws + FR_Q_LO);
        int d = tid >> 1, k0 = (tid & 1) * 64;
        int t = d >> 4, col = d & 15;
        for (int kk = 0; kk < 64; kk += 8) {
            int k = k0 + kk;
            float4 x0 = *(const float4*)&W_tsq[d * 128 + k];
            float4 x1 = *(const float4*)&W_tsq[d * 128 + k + 4];
            short8v h8, l8; split8(x0, x1, h8, l8);
            int c = k >> 5, kg = (k >> 3) & 3;
            int a2 = (((t * 4 + c) * 4 + kg) * 16 + col) * 8;
            *(short8v*)&FH[a2] = h8;
            *(short8v*)&FL[a2] = l8;
        }
        return;
    }
    int which = bid >> 3;          // 0: ts, 1: t
    int sub = bid & 7;
    const float* A    = which ? W_ht : W_hts;
    const float* Bm   = which ? W_mt : W_mts;
    const float* bin  = which ? b_mt : b_mts;
    const float* bout = which ? b_ht : b_hts;
    short* FH = (short*)(ws + (which ? FR_T_HI : FR_TS_HI));
    short* FL = (short*)(ws + (which ? FR_T_LO : FR_TS_LO));
    float* BC = ws + (which ? BC_T : BC_TS);

    int d = sub * 16 + (tid >> 4);
    int k0 = (tid & 15) * 8;
    float a8[8];
    #pragma unroll
    for (int q = 0; q < 8; ++q) a8[q] = 0.f;
    for (int m = 0; m < 128; ++m) {
        float a = A[d * 128 + m];
        float4 b0 = *(const float4*)&Bm[m * 128 + k0];
        float4 b1 = *(const float4*)&Bm[m * 128 + k0 + 4];
        a8[0] = fmaf(a, b0.x, a8[0]); a8[1] = fmaf(a, b0.y, a8[1]);
        a8[2] = fmaf(a, b0.z, a8[2]); a8[3] = fmaf(a, b0.w, a8[3]);
        a8[4] = fmaf(a, b1.x, a8[4]); a8[5] = fmaf(a, b1.y, a8[5]);
        a8[6] = fmaf(a, b1.z, a8[6]); a8[7] = fmaf(a, b1.w, a8[7]);
    }
    float4 x0 = make_float4(a8[0], a8[1], a8[2], a8[3]);
    float4 x1 = make_float4(a8[4], a8[5], a8[6], a8[7]);
    short8v h8, l8; split8(x0, x1, h8, l8);
    int t = d >> 4, col = d & 15, c = k0 >> 5, kg = (k0 >> 3) & 3;
    int a2 = (((t * 4 + c) * 4 + kg) * 16 + col) * 8;
    *(short8v*)&FH[a2] = h8;
    *(short8v*)&FL[a2] = l8;

    if (sub == 0 && tid < 128) {
        float a = bout[tid];
        for (int m = 0; m < 128; ++m) a = fmaf(A[tid * 128 + m], bin[m], a);
        BC[tid] = a;
    }
}

// ---------------------------------------------------------------- k_embed
__global__ __launch_bounds__(128) void k_embed(
    const float* __restrict__ s, const float* __restrict__ t,
    const float* __restrict__ W_es, const float* __restrict__ b_es,
    const float* __restrict__ W_et, const float* __restrict__ b_et,
    float* __restrict__ ws)
{
    __shared__ float xs[1024];
    int bid = blockIdx.x;
    int which = bid >> 7;
    int r = bid & 127;
    const float* x    = which ? (t + (long)r * 1024) : (s + (long)r * 1024);
    const float* W    = which ? W_et : W_es;
    const float* bias = which ? b_et : b_es;
    float* outp = ws + (which ? WS_TE : WS_SE) + r * DD;

    int tid = threadIdx.x;
    for (int i = tid; i < 1024; i += 128) xs[i] = x[i];
    __syncthreads();

    const float* Wr = W + (long)tid * 1024;
    float a0 = 0.f, a1 = 0.f, a2 = 0.f, a3 = 0.f;
    #pragma unroll 4
    for (int k = 0; k < 1024; k += 16) {
        float4 xv0 = *(const float4*)&xs[k],      wv0 = *(const float4*)&Wr[k];
        float4 xv1 = *(const float4*)&xs[k + 4],  wv1 = *(const float4*)&Wr[k + 4];
        float4 xv2 = *(const float4*)&xs[k + 8],  wv2 = *(const float4*)&Wr[k + 8];
        float4 xv3 = *(const float4*)&xs[k + 12], wv3 = *(const float4*)&Wr[k + 12];
        a0 = fmaf(xv0.x, wv0.x, fmaf(xv0.y, wv0.y, fmaf(xv0.z, wv0.z, fmaf(xv0.w, wv0.w, a0))));
        a1 = fmaf(xv1.x, wv1.x, fmaf(xv1.y, wv1.y, fmaf(xv1.z, wv1.z, fmaf(xv1.w, wv1.w, a1))));
        a2 = fmaf(xv2.x, wv2.x, fmaf(xv2.y, wv2.y, fmaf(xv2.z, wv2.z, fmaf(xv2.w, wv2.w, a2))));
        a3 = fmaf(xv3.x, wv3.x, fmaf(xv3.y, wv3.y, fmaf(xv3.z, wv3.z, fmaf(xv3.w, wv3.w, a3))));
    }
    outp[tid] = bias[tid] + ((a0 + a1) + (a2 + a3));
}

// ---------------------------------------------------------------- k_proj4
__global__ __launch_bounds__(128) void k_proj4(
    const float* __restrict__ W_tv,  const float* __restrict__ b_tv,
    const float* __restrict__ W_tq,  const float* __restrict__ b_tq,
    const float* __restrict__ W_tsv, const float* __restrict__ b_tsv,
    const float* __restrict__ W_tsq, const float* __restrict__ b_tsq,
    float* __restrict__ ws)
{
    int bid = blockIdx.x;
    int which = bid >> 7;
    int r = bid & 127;
    const float *W, *bias, *in;
    float* outp;
    switch (which) {
        case 0:  W = W_tv;  bias = b_tv;  in = ws + WS_TE; outp = ws + WS_MTV;  break;
        case 1:  W = W_tq;  bias = b_tq;  in = ws + WS_TE; outp = ws + WS_MTQ;  break;
        case 2:  W = W_tsv; bias = b_tsv; in = ws + WS_TE; outp = ws + WS_MSV;  break;
        default: W = W_tsq; bias = b_tsq; in = ws + WS_SE; outp = ws + WS_MSPQ; break;
    }
    int d = threadIdx.x;
    const float* xr = in + r * DD;
    const float* Wr = W + d * DD;
    float a0 = 0.f, a1 = 0.f, a2 = 0.f, a3 = 0.f;
    #pragma unroll
    for (int k = 0; k < DD; k += 16) {
        float4 xv0 = *(const float4*)&xr[k],      wv0 = *(const float4*)&Wr[k];
        float4 xv1 = *(const float4*)&xr[k + 4],  wv1 = *(const float4*)&Wr[k + 4];
        float4 xv2 = *(const float4*)&xr[k + 8],  wv2 = *(const float4*)&Wr[k + 8];
        float4 xv3 = *(const float4*)&xr[k + 12], wv3 = *(const float4*)&Wr[k + 12];
        a0 = fmaf(xv0.x, wv0.x, fmaf(xv0.y, wv0.y, fmaf(xv0.z, wv0.z, fmaf(xv0.w, wv0.w, a0))));
        a1 = fmaf(xv1.x, wv1.x, fmaf(xv1.y, wv1.y, fmaf(xv1.z, wv1.z, fmaf(xv1.w, wv1.w, a1))));
        a2 = fmaf(xv2.x, wv2.x, fmaf(xv2.y, wv2.y, fmaf(xv2.z, wv2.z, fmaf(xv2.w, wv2.w, a2))));
        a3 = fmaf(xv3.x, wv3.x, fmaf(xv3.y, wv3.y, fmaf(xv3.z, wv3.z, fmaf(xv3.w, wv3.w, a3))));
    }
    outp[r * DD + d] = bias[d] + ((a0 + a1) + (a2 + a3));
}

// ---------------------------------------------------------------- k_projcopy
// proj[n] = mem[n] @ W_tsq^T + b_tsq  AND  dst[n] = mem[n]  (fused copy).
// 100000 rows = 6250 groups exactly.
__global__ __launch_bounds__(512, 2) void k_projcopy(
    const float* __restrict__ mem, const float* __restrict__ b_tsq,
    const float* __restrict__ ws, float* __restrict__ proj, float* __restrict__ dst)
{
    __shared__ short Bh[16384], Bl[16384];
    const short* frh = (const short*)(ws + FR_Q_HI);
    const short* frl = (const short*)(ws + FR_Q_LO);
    int tid = threadIdx.x;
    for (int i2 = tid; i2 < 2048; i2 += 512) {
        ((uint4*)Bh)[i2] = ((const uint4*)frh)[i2];
        ((uint4*)Bl)[i2] = ((const uint4*)frl)[i2];
    }
    __syncthreads();

    int lane = tid & 63, w = tid >> 6;
    int g = blockIdx.x * 8 + w;
    if (g >= 6250) return;

    int col = lane & 15, rq = lane >> 4;
    int rowA = g * 16 + col;
    int kg = rq * 8;
    const float* src = mem + (long)rowA * 128;
    float* drow = dst + (long)rowA * 128;

    short8v ah[4], al[4];
    #pragma unroll
    for (int c = 0; c < 4; ++c) {
        int ko = c * 32 + kg;
        float4 x0 = *(const float4*)&src[ko];
        float4 x1 = *(const float4*)&src[ko + 4];
        *(float4*)&drow[ko]     = x0;          // fused memory copy
        *(float4*)&drow[ko + 4] = x1;
        split8(x0, x1, ah[c], al[c]);
    }

    float bcv[8];
    #pragma unroll
    for (int t = 0; t < 8; ++t) bcv[t] = b_tsq[t * 16 + col];

    #pragma unroll
    for (int t = 0; t < 8; ++t) {
        f32x4 a; a[0] = bcv[t]; a[1] = bcv[t]; a[2] = bcv[t]; a[3] = bcv[t];
        #pragma unroll
        for (int c = 0; c < 4; ++c) {
            int off = ((t * 4 + c) * 64 + lane) * 8;
            short8v bh = *(const short8v*)&Bh[off];
            short8v bl = *(const short8v*)&Bl[off];
            a = __builtin_amdgcn_mfma_f32_16x16x32_bf16(al[c], bh, a, 0, 0, 0);
            a = __builtin_amdgcn_mfma_f32_16x16x32_bf16(ah[c], bl, a, 0, 0, 0);
            a = __builtin_amdgcn_mfma_f32_16x16x32_bf16(ah[c], bh, a, 0, 0, 0);
        }
        #pragma unroll
        for (int r = 0; r < 4; ++r)
            proj[((long)(g * 16 + rq * 4 + r)) * 128 + t * 16 + col] = a[r];
    }
}

// ---------------------------------------------------------------- k_ht_mfma
__global__ __launch_bounds__(512, 2) void k_ht_mfma(float* __restrict__ ws)
{
    __shared__ short Bh[16384], Bl[16384];
    const short* frh = (const short*)(ws + FR_T_HI);
    const short* frl = (const short*)(ws + FR_T_LO);
    int tid = threadIdx.x;
    for (int i2 = tid; i2 < 2048; i2 += 512) {
        ((uint4*)Bh)[i2] = ((const uint4*)frh)[i2];
        ((uint4*)Bl)[i2] = ((const uint4*)frl)[i2];
    }
    __syncthreads();

    const float* mtv = ws + WS_MTV;
    const float* mtq = ws + WS_MTQ;
    const float* bc  = ws + BC_T;
    float* ht = ws + WS_HT;

    int lane = tid & 63, w = tid >> 6;
    int col = lane & 15, rq = lane >> 4;
    int g = blockIdx.x * 8 + w;
    int p = g * 16 + col;
    int i = p >> 7, j = p & 127;
    int kg = rq * 8;
    const float* vj = mtv + j * 128;
    const float* qi = mtq + i * 128;

    short8v ah[4], al[4];
    #pragma unroll
    for (int c = 0; c < 4; ++c) {
        int ko = c * 32 + kg;
        float4 v0 = *(const float4*)&vj[ko], v1 = *(const float4*)&vj[ko + 4];
        float4 q0 = *(const float4*)&qi[ko], q1 = *(const float4*)&qi[ko + 4];
        float4 r0 = make_float4(fmaxf(v0.x - q0.x, 0.f), fmaxf(v0.y - q0.y, 0.f),
                                fmaxf(v0.z - q0.z, 0.f), fmaxf(v0.w - q0.w, 0.f));
        float4 r1 = make_float4(fmaxf(v1.x - q1.x, 0.f), fmaxf(v1.y - q1.y, 0.f),
                                fmaxf(v1.z - q1.z, 0.f), fmaxf(v1.w - q1.w, 0.f));
        split8(r0, r1, ah[c], al[c]);
    }

    float bcv[8];
    #pragma unroll
    for (int t = 0; t < 8; ++t) bcv[t] = bc[t * 16 + col];

    f32x4 acc[8];
    #pragma unroll
    for (int t = 0; t < 8; ++t) {
        f32x4 a; a[0] = bcv[t]; a[1] = bcv[t]; a[2] = bcv[t]; a[3] = bcv[t];
        #pragma unroll
        for (int c = 0; c < 4; ++c) {
            int off = ((t * 4 + c) * 64 + lane) * 8;
            short8v bh = *(const short8v*)&Bh[off];
            short8v bl = *(const short8v*)&Bl[off];
            a = __builtin_amdgcn_mfma_f32_16x16x32_bf16(al[c], bh, a, 0, 0, 0);
            a = __builtin_amdgcn_mfma_f32_16x16x32_bf16(ah[c], bl, a, 0, 0, 0);
            a = __builtin_amdgcn_mfma_f32_16x16x32_bf16(ah[c], bh, a, 0, 0, 0);
        }
        acc[t] = a;
    }

    #pragma unroll
    for (int r = 0; r < 4; ++r) {
        long rho = g * 16 + rq * 4 + r;
        float s_uu = 0.f;
        #pragma unroll
        for (int t = 0; t < 8; ++t) { float u = acc[t][r]; s_uu = fmaf(u, u, s_uu); }
        #pragma unroll
        for (int m = 1; m < 16; m <<= 1) s_uu += __shfl_xor(s_uu, m);
        float rn = rsqrtf(s_uu);
        #pragma unroll
        for (int t = 0; t < 8; ++t)
            ht[rho * 128 + t * 16 + col] = acc[t][r] * rn;
    }
}

// ---------------------------------------------------------------- k_neg_mfma
// 278528 rows = 17408 groups of 16; each wave handles TWO groups (R=2) so
// every B-fragment ds_read feeds 6 MFMAs. Grid 1088 x 512.
__global__ __launch_bounds__(512, 2) void k_neg_mfma(
    const float* __restrict__ ws, const int* __restrict__ idx,
    const float* __restrict__ proj, float* __restrict__ out)
{
    __shared__ short Bh[16384], Bl[16384];
    const short* frh = (const short*)(ws + FR_TS_HI);
    const short* frl = (const short*)(ws + FR_TS_LO);
    int tid = threadIdx.x;
    for (int i2 = tid; i2 < 2048; i2 += 512) {
        ((uint4*)Bh)[i2] = ((const uint4*)frh)[i2];
        ((uint4*)Bl)[i2] = ((const uint4*)frl)[i2];
    }
    __syncthreads();

    const float* msv  = ws + WS_MSV;
    const float* mspq = ws + WS_MSPQ;
    const float* ht   = ws + WS_HT;
    const float* bc   = ws + BC_TS;

    int lane = tid & 63, w = tid >> 6;
    int col = lane & 15, rq = lane >> 4;
    int g0 = blockIdx.x * 16 + w * 2;
    int kg = rq * 8;

    short8v ah[2][4], al[2][4];
    int pe_[2][4];
    #pragma unroll
    for (int gi = 0; gi < 2; ++gi) {
        int g = g0 + gi;
        int rowA = g * 16 + col;
        int p = rowA / 17;
        int slot = rowA - p * 17;
        const float* src = (slot == 0) ? (mspq + (p >> 7) * 128)
                                       : (proj + (long)idx[p * 17 + slot - 1] * 128);
        const float* vj = msv + (p & 127) * 128;
        #pragma unroll
        for (int c = 0; c < 4; ++c) {
            int ko = c * 32 + kg;
            float4 v0 = *(const float4*)&vj[ko],  v1 = *(const float4*)&vj[ko + 4];
            float4 q0 = *(const float4*)&src[ko], q1 = *(const float4*)&src[ko + 4];
            float4 r0 = make_float4(fmaxf(v0.x - q0.x, 0.f), fmaxf(v0.y - q0.y, 0.f),
                                    fmaxf(v0.z - q0.z, 0.f), fmaxf(v0.w - q0.w, 0.f));
            float4 r1 = make_float4(fmaxf(v1.x - q1.x, 0.f), fmaxf(v1.y - q1.y, 0.f),
                                    fmaxf(v1.z - q1.z, 0.f), fmaxf(v1.w - q1.w, 0.f));
            split8(r0, r1, ah[gi][c], al[gi][c]);
        }
        #pragma unroll
        for (int r = 0; r < 4; ++r)
            pe_[gi][r] = (g * 16 + rq * 4 + r) / 17;
    }

    float bcv[8];
    #pragma unroll
    for (int t = 0; t < 8; ++t) bcv[t] = bc[t * 16 + col];

    float s_uu[2][4], s_hu[2][4];
    #pragma unroll
    for (int gi = 0; gi < 2; ++gi)
        #pragma unroll
        for (int r = 0; r < 4; ++r) { s_uu[gi][r] = 0.f; s_hu[gi][r] = 0.f; }

    #pragma unroll
    for (int t = 0; t < 8; ++t) {
        f32x4 acc[2];
        #pragma unroll
        for (int gi = 0; gi < 2; ++gi) {
            f32x4 a; a[0] = bcv[t]; a[1] = bcv[t]; a[2] = bcv[t]; a[3] = bcv[t];
            acc[gi] = a;
        }
        #pragma unroll
        for (int c = 0; c < 4; ++c) {
            int off = ((t * 4 + c) * 64 + lane) * 8;
            short8v bh = *(const short8v*)&Bh[off];
            short8v bl = *(const short8v*)&Bl[off];
            acc[0] = __builtin_amdgcn_mfma_f32_16x16x32_bf16(al[0][c], bh, acc[0], 0, 0, 0);
            acc[0] = __builtin_amdgcn_mfma_f32_16x16x32_bf16(ah[0][c], bl, acc[0], 0, 0, 0);
            acc[0] = __builtin_amdgcn_mfma_f32_16x16x32_bf16(ah[0][c], bh, acc[0], 0, 0, 0);
            acc[1] = __builtin_amdgcn_mfma_f32_16x16x32_bf16(al[1][c], bh, acc[1], 0, 0, 0);
            acc[1] = __builtin_amdgcn_mfma_f32_16x16x32_bf16(ah[1][c], bl, acc[1], 0, 0, 0);
            acc[1] = __builtin_amdgcn_mfma_f32_16x16x32_bf16(ah[1][c], bh, acc[1], 0, 0, 0);
        }
        #pragma unroll
        for (int gi = 0; gi < 2; ++gi)
            #pragma unroll
            for (int r = 0; r < 4; ++r) {
                float u = acc[gi][r];
                float h = ht[(long)pe_[gi][r] * 128 + t * 16 + col];
                s_uu[gi][r] = fmaf(u, u, s_uu[gi][r]);
                s_hu[gi][r] = fmaf(h, u, s_hu[gi][r]);
            }
    }

    #pragma unroll
    for (int gi = 0; gi < 2; ++gi)
        #pragma unroll
        for (int r = 0; r < 4; ++r) {
            float su = s_uu[gi][r], sh = s_hu[gi][r];
            #pragma unroll
            for (int m = 1; m < 16; m <<= 1) {
                su += __shfl_xor(su, m);
                sh += __shfl_xor(sh, m);
            }
            if (col == 0)
                out[(g0 + gi) * 16 + rq * 4 + r] = __expf((sh * rsqrtf(su) - 1.0f) * INV_T);
        }
}

// ---------------------------------------------------------------- k_memupd
__global__ __launch_bounds__(128) void k_memupd(
    const float* __restrict__ mem, const float* __restrict__ se,
    const int* __restrict__ y, float* __restrict__ dst)
{
    int b = blockIdx.x;
    int d = threadIdx.x;
    int yb = y[b];
    for (int b2 = b + 1; b2 < BB; ++b2)
        if (y[b2] == yb) return;

    float ab = 0.5f * mem[(long)yb * 128 + d] + 0.5f * se[b * 128 + d];
    float ss = ab * ab;
    #pragma unroll
    for (int mq = 32; mq; mq >>= 1) ss += __shfl_xor(ss, mq);
    __shared__ float partial[2];
    if ((d & 63) == 0) partial[d >> 6] = ss;
    __syncthreads();
    float tot = partial[0] + partial[1];
    dst[(long)yb * 128 + d] = ab * rsqrtf(tot);
}

// ---------------------------------------------------------------- launch
extern "C" void kernel_launch(void* const* d_in, const int* in_sizes, int n_in,
                              void* d_out, int out_size, void* d_ws, size_t ws_size,
                              hipStream_t stream)
{
    const float* s     = (const float*)d_in[0];
    const float* t     = (const float*)d_in[1];
    const int*   y     = (const int*)  d_in[2];
    const int*   idx   = (const int*)  d_in[3];
    const float* mem   = (const float*)d_in[4];
    const float* W_es  = (const float*)d_in[5];  const float* b_es  = (const float*)d_in[6];
    const float* W_et  = (const float*)d_in[7];  const float* b_et  = (const float*)d_in[8];
    const float* W_tv  = (const float*)d_in[9];  const float* b_tv  = (const float*)d_in[10];
    const float* W_tq  = (const float*)d_in[11]; const float* b_tq  = (const float*)d_in[12];
    const float* W_tsv = (const float*)d_in[13]; const float* b_tsv = (const float*)d_in[14];
    const float* W_tsq = (const float*)d_in[15]; const float* b_tsq = (const float*)d_in[16];
    const float* W_mt  = (const float*)d_in[17]; const float* b_mt  = (const float*)d_in[18];
    const float* W_mts = (const float*)d_in[19]; const float* b_mts = (const float*)d_in[20];
    const float* W_ht  = (const float*)d_in[21]; const float* b_ht  = (const float*)d_in[22];
    const float* W_hts = (const float*)d_in[23]; const float* b_hts = (const float*)d_in[24];

    float* out  = (float*)d_out;
    float* ws   = (float*)d_ws;
    float* proj = out + OUT_MEM;   // scratch alias; memory_new written by projcopy/memupd

    k_compose <<<17, 256, 0, stream>>>(W_mts, b_mts, W_hts, b_hts,
                                       W_mt, b_mt, W_ht, b_ht, W_tsq, ws);
    k_embed   <<<256, 128, 0, stream>>>(s, t, W_es, b_es, W_et, b_et, ws);
    // NOTE: projcopy writes proj into the SAME region the copy targets? No:
    // proj aliases out+OUT_MEM... it must NOT. proj goes to ws scratch instead.
    k_projcopy<<<782, 512, 0, stream>>>(mem, b_tsq, ws, ws + 2244864, out + OUT_MEM);
    k_proj4   <<<512, 128, 0, stream>>>(W_tv, b_tv, W_tq, b_tq, W_tsv, b_tsv, W_tsq, b_tsq, ws);
    k_ht_mfma <<<128, 512, 0, stream>>>(ws);
    k_neg_mfma<<<1088, 512, 0, stream>>>(ws, idx, ws + 2244864, out);
    k_memupd  <<<128, 128, 0, stream>>>(mem, ws + WS_SE, y, out + OUT_MEM);
}